// Round 1
// baseline (1830.382 us; speedup 1.0000x reference)
//
#include <hip/hip_runtime.h>

// LinearInFieldChargesBlock: per-node fully-connected tensor product.
// out0[w] = C000 * sum_{u,v} x0[u] y0[v] w000[u,v,w] + C110 * sum_{u,v,i} x1[u,i] y1[v,i] w110[u,v,w]
// out1[w,k] = C011 * sum_{u,v} x0[u] y1[v,k] w011[u,v,w] + C101 * sum_{u,v} x1[u,k] y0[v] w101[u,v,w]
// out = 0.01 * concat(out0, out1), out[:,0] = 0
//
// Strategy: memory-bound (870 MB stream, ~140 us floor). y-first factorization:
// per u compute B-tensors (y (x) w) then FMA with x — 21.5k MACs/node, fp32 VALU.
// Roles: waves 0-1 of each block stream x0 (80 MACs/u), waves 2-3 stream x1
// (88 MACs/u); partial outputs reduced via LDS. node_feat staged via LDS in 8
// double-buffered chunks (coalesced float4), weights via wave-uniform s_loads.

#define NBLK 128          // nodes per block
#define BLOCK 256
#define NITER 8           // u-chunks of 16
#define X0_STRIDE 17      // 16 + 1 pad (odd -> conflict-free b32 reads)
#define X1_STRIDE 49      // 48 + 1 pad
#define X0_REGION (NBLK * X0_STRIDE)                 // 2176 dwords
#define BUF_DW (NBLK * (X0_STRIDE + X1_STRIDE))      // 8448 dwords per buffer

__global__ __launch_bounds__(BLOCK, 2)
void fctp_kernel(const float* __restrict__ nf, const float* __restrict__ pf,
                 const float* __restrict__ w000, const float* __restrict__ w011,
                 const float* __restrict__ w101, const float* __restrict__ w110,
                 float* __restrict__ out)
{
    __shared__ float lds[2 * BUF_DW];   // 67584 B -> 2 blocks/CU

    const int t  = threadIdx.x;
    const int n0 = blockIdx.x * NBLK;
    const int m  = t & (NBLK - 1);                       // node-local index
    const int roleS = __builtin_amdgcn_readfirstlane(t >> 7);  // 0 = x0-stream, 1 = x1-stream (wave-uniform)

    // ---- per-thread y values (this thread's node) ----
    const float4* pf4 = (const float4*)(pf + (size_t)(n0 + m) * 16);
    float4 ya = pf4[0], yb = pf4[1], yc = pf4[2], yd = pf4[3];
    const float y00 = ya.x, y01 = ya.y, y02 = ya.z, y03 = ya.w;
    float y1v[4][3] = {{yb.x, yb.y, yb.z},
                       {yb.w, yc.x, yc.y},
                       {yc.z, yc.w, yd.x},
                       {yd.y, yd.z, yd.w}};

    // ---- staging maps: per iter stage x0 (128 nodes x 16 f) + x1 (128 x 48 f) ----
    int mm0[2], jj0[2], mm1[6], jj1[6];
#pragma unroll
    for (int s = 0; s < 2; ++s) { int idx = t + BLOCK * s; mm0[s] = idx >> 2; jj0[s] = idx & 3; }
#pragma unroll
    for (int s = 0; s < 6; ++s) { int idx = t + BLOCK * s; mm1[s] = idx / 12; jj1[s] = idx % 12; }

    float4 rx0[2], rx1[6];
    auto load_iter = [&](int k) {
#pragma unroll
        for (int s = 0; s < 2; ++s)
            rx0[s] = *(const float4*)(nf + (size_t)(n0 + mm0[s]) * 512 + 16 * k + 4 * jj0[s]);
#pragma unroll
        for (int s = 0; s < 6; ++s)
            rx1[s] = *(const float4*)(nf + (size_t)(n0 + mm1[s]) * 512 + 128 + 48 * k + 4 * jj1[s]);
    };
    auto store_iter = [&](int k) {
        float* b = lds + (k & 1) * BUF_DW;
#pragma unroll
        for (int s = 0; s < 2; ++s) {
            float* p = b + mm0[s] * X0_STRIDE + 4 * jj0[s];
            p[0] = rx0[s].x; p[1] = rx0[s].y; p[2] = rx0[s].z; p[3] = rx0[s].w;
        }
#pragma unroll
        for (int s = 0; s < 6; ++s) {
            float* p = b + X0_REGION + mm1[s] * X1_STRIDE + 4 * jj1[s];
            p[0] = rx1[s].x; p[1] = rx1[s].y; p[2] = rx1[s].z; p[3] = rx1[s].w;
        }
    };

    float o0[4]    = {0.f, 0.f, 0.f, 0.f};
    float o1[4][3] = {{0.f,0.f,0.f},{0.f,0.f,0.f},{0.f,0.f,0.f},{0.f,0.f,0.f}};

    load_iter(0);
    store_iter(0);

#pragma unroll 1
    for (int k = 0; k < NITER; ++k) {
        __syncthreads();                       // buffer k visible; prev compute done
        if (k + 1 < NITER) load_iter(k + 1);   // prefetch flies during compute
        const float* buf = lds + (k & 1) * BUF_DW;

        if (roleS == 0) {
            // ---- x0 stream: B000 -> out0, B011 -> out1 ----
            const float* xp = buf + m * X0_STRIDE;
#pragma unroll
            for (int j = 0; j < 16; ++j) {
                const int u = 16 * k + j;
                const float xv = xp[j];
                const float* wa = w000 + u * 16;   // wave-uniform -> s_load
                const float* wb = w011 + u * 16;
#pragma unroll
                for (int w = 0; w < 4; ++w) {
                    float bb = y00 * wa[w];
                    bb = fmaf(y01, wa[4 + w], bb);
                    bb = fmaf(y02, wa[8 + w], bb);
                    bb = fmaf(y03, wa[12 + w], bb);
                    o0[w] = fmaf(xv, bb, o0[w]);
                }
#pragma unroll
                for (int w = 0; w < 4; ++w) {
#pragma unroll
                    for (int c = 0; c < 3; ++c) {
                        float bb = y1v[0][c] * wb[w];
                        bb = fmaf(y1v[1][c], wb[4 + w], bb);
                        bb = fmaf(y1v[2][c], wb[8 + w], bb);
                        bb = fmaf(y1v[3][c], wb[12 + w], bb);
                        o1[w][c] = fmaf(xv, bb, o1[w][c]);
                    }
                }
            }
        } else {
            // ---- x1 stream: B110 -> out0, B101 -> out1 ----
            const float* xp = buf + X0_REGION + m * X1_STRIDE;
#pragma unroll
            for (int j = 0; j < 16; ++j) {
                const int u = 16 * k + j;
                const float xa = xp[3 * j], xb = xp[3 * j + 1], xc = xp[3 * j + 2];
                const float* wc = w110 + u * 16;
                const float* wd = w101 + u * 16;
#pragma unroll
                for (int w = 0; w < 4; ++w) {
                    float t0 = y1v[0][0] * wc[w];
                    t0 = fmaf(y1v[1][0], wc[4 + w], t0);
                    t0 = fmaf(y1v[2][0], wc[8 + w], t0);
                    t0 = fmaf(y1v[3][0], wc[12 + w], t0);
                    o0[w] = fmaf(xa, t0, o0[w]);
                    float t1 = y1v[0][1] * wc[w];
                    t1 = fmaf(y1v[1][1], wc[4 + w], t1);
                    t1 = fmaf(y1v[2][1], wc[8 + w], t1);
                    t1 = fmaf(y1v[3][1], wc[12 + w], t1);
                    o0[w] = fmaf(xb, t1, o0[w]);
                    float t2 = y1v[0][2] * wc[w];
                    t2 = fmaf(y1v[1][2], wc[4 + w], t2);
                    t2 = fmaf(y1v[2][2], wc[8 + w], t2);
                    t2 = fmaf(y1v[3][2], wc[12 + w], t2);
                    o0[w] = fmaf(xc, t2, o0[w]);
                    float ss = y00 * wd[w];
                    ss = fmaf(y01, wd[4 + w], ss);
                    ss = fmaf(y02, wd[8 + w], ss);
                    ss = fmaf(y03, wd[12 + w], ss);
                    o1[w][0] = fmaf(xa, ss, o1[w][0]);
                    o1[w][1] = fmaf(xb, ss, o1[w][1]);
                    o1[w][2] = fmaf(xc, ss, o1[w][2]);
                }
            }
        }
        if (k + 1 < NITER) store_iter(k + 1);
    }

    // ---- epilogue: scale partials, reduce A+B via LDS, write out ----
    // Coefficients with the global 0.01 folded in.
    const float K000 = 0.01f / 32.0f;
    const float K011 = 0.01f / 32.0f;
    const float K101 = 0.01f / 32.0f;
    const float K110 = 1.8042195912175807e-4f;   // 0.01 / (32*sqrt(3))

    if (roleS != 0) {
        // B partials -> LDS (buffer-0 x0 region: free, last compute reads buffer 1)
        float* rp = lds + m * X0_STRIDE;
#pragma unroll
        for (int w = 0; w < 4; ++w) rp[w] = K110 * o0[w];
#pragma unroll
        for (int w = 0; w < 4; ++w) {
            rp[4 + 3 * w + 0] = K101 * o1[w][0];
            rp[4 + 3 * w + 1] = K101 * o1[w][1];
            rp[4 + 3 * w + 2] = K101 * o1[w][2];
        }
    }
    __syncthreads();
    if (roleS == 0) {
        const float* rp = lds + m * X0_STRIDE;
        float r[16];
        r[0] = 0.0f;                                   // out[:,0] zeroed
#pragma unroll
        for (int w = 1; w < 4; ++w) r[w] = fmaf(K000, o0[w], rp[w]);
#pragma unroll
        for (int w = 0; w < 4; ++w) {
#pragma unroll
            for (int c = 0; c < 3; ++c) {
                const int idx = 4 + 3 * w + c;
                r[idx] = fmaf(K011, o1[w][c], rp[idx]);
            }
        }
        float4 v0 = {r[0],  r[1],  r[2],  r[3]};
        float4 v1 = {r[4],  r[5],  r[6],  r[7]};
        float4 v2 = {r[8],  r[9],  r[10], r[11]};
        float4 v3 = {r[12], r[13], r[14], r[15]};
        float4* op = (float4*)(out + (size_t)(n0 + m) * 16);
        op[0] = v0; op[1] = v1; op[2] = v2; op[3] = v3;
    }
}

extern "C" void kernel_launch(void* const* d_in, const int* in_sizes, int n_in,
                              void* d_out, int out_size, void* d_ws, size_t ws_size,
                              hipStream_t stream)
{
    const float* nf   = (const float*)d_in[0];
    const float* pf   = (const float*)d_in[1];
    const float* w000 = (const float*)d_in[2];
    const float* w011 = (const float*)d_in[3];
    const float* w101 = (const float*)d_in[4];
    const float* w110 = (const float*)d_in[5];
    float* out = (float*)d_out;

    const int n_nodes = in_sizes[0] / 512;   // 400000
    fctp_kernel<<<n_nodes / NBLK, BLOCK, 0, stream>>>(nf, pf, w000, w011, w101, w110, out);
}

// Round 2
// 1709.221 us; speedup vs baseline: 1.0709x; 1.0709x over previous
//
#include <hip/hip_runtime.h>

// LinearInFieldChargesBlock: per-node fully-connected tensor product.
// out0[w] = C000 * sum_{u,v} x0[u] y0[v] w000[u,v,w] + C110 * sum_{u,v,i} x1[u,i] y1[v,i] w110[u,v,w]
// out1[w,k] = C011 * sum_{u,v} x0[u] y1[v,k] w011[u,v,w] + C101 * sum_{u,v} x1[u,k] y0[v] w101[u,v,w]
// out = 0.01 * concat(out0, out1), out[:,0] = 0
//
// R1 redesign: previous version spilled its register prefetch (rx0/rx1) to
// scratch -> 1.17 GB of HBM writes (WRITE_SIZE counter) + serialization.
// Now: global->LDS staging via __builtin_amdgcn_global_load_lds (16B DMA,
// no VGPR round-trip, no scratch). Linear LDS layout (DMA requires it);
// reads are ds_read_b128 at row stride 8/24 dw -> ~2x b128 bank aliasing,
// negligible vs compute. Chunk = 8 u/iter, NITER=16, buffer 16 KB, LDS 32 KB
// -> up to 5 blocks/CU (20 waves) vs previous 2 (8 waves).
// Roles unchanged: waves 0-1 stream x0 terms, waves 2-3 stream x1 terms,
// partials reduced via LDS in epilogue. Weights via wave-uniform s_loads.

#define NBLK 128          // nodes per block
#define BLOCK 256
#define NITER 16          // u-chunks of 8
#define CHUNK 8
#define X0_DW 1024        // 128 nodes x 8 dw (linear, no pad: DMA dest)
#define BUF_DW 4096       // x0 (1024 dw) + x1 (128 x 24 dw = 3072 dw)

#define GLOBAL_ASP const __attribute__((address_space(1))) void*
#define LDS_ASP __attribute__((address_space(3))) void*

__global__ __launch_bounds__(BLOCK, 4)
void fctp_kernel(const float* __restrict__ nf, const float* __restrict__ pf,
                 const float* __restrict__ w000, const float* __restrict__ w011,
                 const float* __restrict__ w101, const float* __restrict__ w110,
                 float* __restrict__ out)
{
    __shared__ float lds[2 * BUF_DW];   // 32768 B -> LDS allows 5 blocks/CU

    const int t  = threadIdx.x;
    const int n0 = blockIdx.x * NBLK;
    const int m  = t & (NBLK - 1);                             // node-local index
    const int roleS = __builtin_amdgcn_readfirstlane(t >> 7);  // 0 = x0-stream, 1 = x1-stream
    const int W  = __builtin_amdgcn_readfirstlane(t >> 6);     // wave id 0..3
    const int l  = t & 63;

    // ---- per-thread y values (this thread's node) ----
    const float4* pf4 = (const float4*)(pf + (size_t)(n0 + m) * 16);
    float4 ya = pf4[0], yb = pf4[1], yc = pf4[2], yd = pf4[3];
    const float y00 = ya.x, y01 = ya.y, y02 = ya.z, y03 = ya.w;
    float y1v[4][3] = {{yb.x, yb.y, yb.z},
                       {yb.w, yc.x, yc.y},
                       {yc.z, yc.w, yd.x},
                       {yd.y, yd.z, yd.w}};

    // ---- DMA lane maps (LDS dest is wave-uniform base + lane*16) ----
    // x0 region: node mm row = 8 dw; lane l covers region dword W*256 + 4l
    //   -> mm = W*32 + (l>>1), granule b = l&1. Source: nf row + 8k + 4b floats.
    const int  m0dma = W * 32 + (l >> 1);
    const int  b0dma = l & 1;
    const float* gx0 = nf + (size_t)(n0 + m0dma) * 512 + 4 * b0dma;   // +8 floats per iter

    // x1 region: node mm row = 24 dw; instr s covers region dwords (W*3+s)*256 + 4l
    //   -> mm = r/24, granule g = (r%24)/4. Source: nf row + 128 + 24k + 4g floats.
    const float* gx1[3];
    int d1[3];
#pragma unroll
    for (int s = 0; s < 3; ++s) {
        const int r  = (W * 3 + s) * 256 + 4 * l;
        const int mm = r / 24;
        const int gg = (r - 24 * mm) >> 2;
        gx1[s] = nf + (size_t)(n0 + mm) * 512 + 128 + 4 * gg;          // +24 floats per iter
        d1[s]  = X0_DW + (W * 3 + s) * 256;
    }
    const int d0 = W * 256;

    auto dma = [&](int buf, int k) {
        __builtin_amdgcn_global_load_lds((GLOBAL_ASP)(gx0 + 8 * k),
                                         (LDS_ASP)(lds + buf * BUF_DW + d0), 16, 0, 0);
#pragma unroll
        for (int s = 0; s < 3; ++s)
            __builtin_amdgcn_global_load_lds((GLOBAL_ASP)(gx1[s] + 24 * k),
                                             (LDS_ASP)(lds + buf * BUF_DW + d1[s]), 16, 0, 0);
    };

    float o0[4]    = {0.f, 0.f, 0.f, 0.f};
    float o1[4][3] = {{0.f,0.f,0.f},{0.f,0.f,0.f},{0.f,0.f,0.f},{0.f,0.f,0.f}};

    dma(0, 0);

#pragma unroll 1
    for (int k = 0; k < NITER; ++k) {
        __syncthreads();                       // vmcnt(0) drain -> buffer k ready
        if (k + 1 < NITER) dma((k + 1) & 1, k + 1);   // async prefetch flies during compute
        const float* buf = lds + (k & 1) * BUF_DW;

        if (roleS == 0) {
            // ---- x0 stream: B000 -> out0, B011 -> out1 ----
            const float* xp = buf + m * 8;
            const float4 va = *(const float4*)xp;
            const float4 vb = *(const float4*)(xp + 4);
            float xs[8] = {va.x, va.y, va.z, va.w, vb.x, vb.y, vb.z, vb.w};
#pragma unroll
            for (int j = 0; j < CHUNK; ++j) {
                const int u = CHUNK * k + j;
                const float xv = xs[j];
                const float* wa = w000 + u * 16;   // wave-uniform -> s_load
                const float* wb = w011 + u * 16;
#pragma unroll
                for (int w = 0; w < 4; ++w) {
                    float bb = y00 * wa[w];
                    bb = fmaf(y01, wa[4 + w], bb);
                    bb = fmaf(y02, wa[8 + w], bb);
                    bb = fmaf(y03, wa[12 + w], bb);
                    o0[w] = fmaf(xv, bb, o0[w]);
                }
#pragma unroll
                for (int w = 0; w < 4; ++w) {
#pragma unroll
                    for (int c = 0; c < 3; ++c) {
                        float bb = y1v[0][c] * wb[w];
                        bb = fmaf(y1v[1][c], wb[4 + w], bb);
                        bb = fmaf(y1v[2][c], wb[8 + w], bb);
                        bb = fmaf(y1v[3][c], wb[12 + w], bb);
                        o1[w][c] = fmaf(xv, bb, o1[w][c]);
                    }
                }
            }
        } else {
            // ---- x1 stream: B110 -> out0, B101 -> out1 ----
            const float* xq = buf + X0_DW + m * 24;
            const float4 q0 = *(const float4*)(xq);
            const float4 q1 = *(const float4*)(xq + 4);
            const float4 q2 = *(const float4*)(xq + 8);
            const float4 q3 = *(const float4*)(xq + 12);
            const float4 q4 = *(const float4*)(xq + 16);
            const float4 q5 = *(const float4*)(xq + 20);
            float xf[24] = {q0.x,q0.y,q0.z,q0.w, q1.x,q1.y,q1.z,q1.w,
                            q2.x,q2.y,q2.z,q2.w, q3.x,q3.y,q3.z,q3.w,
                            q4.x,q4.y,q4.z,q4.w, q5.x,q5.y,q5.z,q5.w};
#pragma unroll
            for (int j = 0; j < CHUNK; ++j) {
                const int u = CHUNK * k + j;
                const float xa = xf[3 * j], xb = xf[3 * j + 1], xc = xf[3 * j + 2];
                const float* wc = w110 + u * 16;
                const float* wd = w101 + u * 16;
#pragma unroll
                for (int w = 0; w < 4; ++w) {
                    float t0 = y1v[0][0] * wc[w];
                    t0 = fmaf(y1v[1][0], wc[4 + w], t0);
                    t0 = fmaf(y1v[2][0], wc[8 + w], t0);
                    t0 = fmaf(y1v[3][0], wc[12 + w], t0);
                    o0[w] = fmaf(xa, t0, o0[w]);
                    float t1 = y1v[0][1] * wc[w];
                    t1 = fmaf(y1v[1][1], wc[4 + w], t1);
                    t1 = fmaf(y1v[2][1], wc[8 + w], t1);
                    t1 = fmaf(y1v[3][1], wc[12 + w], t1);
                    o0[w] = fmaf(xb, t1, o0[w]);
                    float t2 = y1v[0][2] * wc[w];
                    t2 = fmaf(y1v[1][2], wc[4 + w], t2);
                    t2 = fmaf(y1v[2][2], wc[8 + w], t2);
                    t2 = fmaf(y1v[3][2], wc[12 + w], t2);
                    o0[w] = fmaf(xc, t2, o0[w]);
                    float ss = y00 * wd[w];
                    ss = fmaf(y01, wd[4 + w], ss);
                    ss = fmaf(y02, wd[8 + w], ss);
                    ss = fmaf(y03, wd[12 + w], ss);
                    o1[w][0] = fmaf(xa, ss, o1[w][0]);
                    o1[w][1] = fmaf(xb, ss, o1[w][1]);
                    o1[w][2] = fmaf(xc, ss, o1[w][2]);
                }
            }
        }
    }

    // ---- epilogue: scale partials, reduce A+B via LDS, write out ----
    // Last compute read buffer 1 (k=15); buffer 0 is free for the reduction.
    // Stride 17 (odd) -> conflict-free b32 access. 128*17 = 2176 dw < 4096 ok.
    const float K000 = 0.01f / 32.0f;
    const float K011 = 0.01f / 32.0f;
    const float K101 = 0.01f / 32.0f;
    const float K110 = 1.8042195912175807e-4f;   // 0.01 / (32*sqrt(3))

    if (roleS != 0) {
        float* rp = lds + m * 17;
#pragma unroll
        for (int w = 0; w < 4; ++w) rp[w] = K110 * o0[w];
#pragma unroll
        for (int w = 0; w < 4; ++w) {
            rp[4 + 3 * w + 0] = K101 * o1[w][0];
            rp[4 + 3 * w + 1] = K101 * o1[w][1];
            rp[4 + 3 * w + 2] = K101 * o1[w][2];
        }
    }
    __syncthreads();
    if (roleS == 0) {
        const float* rp = lds + m * 17;
        float r[16];
        r[0] = 0.0f;                                   // out[:,0] zeroed
#pragma unroll
        for (int w = 1; w < 4; ++w) r[w] = fmaf(K000, o0[w], rp[w]);
#pragma unroll
        for (int w = 0; w < 4; ++w) {
#pragma unroll
            for (int c = 0; c < 3; ++c) {
                const int idx = 4 + 3 * w + c;
                r[idx] = fmaf(K011, o1[w][c], rp[idx]);
            }
        }
        float4 v0 = {r[0],  r[1],  r[2],  r[3]};
        float4 v1 = {r[4],  r[5],  r[6],  r[7]};
        float4 v2 = {r[8],  r[9],  r[10], r[11]};
        float4 v3 = {r[12], r[13], r[14], r[15]};
        float4* op = (float4*)(out + (size_t)(n0 + m) * 16);
        op[0] = v0; op[1] = v1; op[2] = v2; op[3] = v3;
    }
}

extern "C" void kernel_launch(void* const* d_in, const int* in_sizes, int n_in,
                              void* d_out, int out_size, void* d_ws, size_t ws_size,
                              hipStream_t stream)
{
    const float* nf   = (const float*)d_in[0];
    const float* pf   = (const float*)d_in[1];
    const float* w000 = (const float*)d_in[2];
    const float* w011 = (const float*)d_in[3];
    const float* w101 = (const float*)d_in[4];
    const float* w110 = (const float*)d_in[5];
    float* out = (float*)d_out;

    const int n_nodes = in_sizes[0] / 512;   // 400000
    fctp_kernel<<<n_nodes / NBLK, BLOCK, 0, stream>>>(nf, pf, w000, w011, w101, w110, out);
}